// Round 6
// baseline (510.755 us; speedup 1.0000x reference)
//
#include <hip/hip_runtime.h>
#include <hip/hip_bf16.h>

#define NN 4096
#define HD 128
#define KG 4
#define NC 10
#define CAP 64

typedef __attribute__((ext_vector_type(8))) short bf16x8;
typedef __attribute__((ext_vector_type(4))) float f32x4;

__device__ inline unsigned short f2b(float x) {   // fp32 -> bf16 RNE
    unsigned u = __float_as_uint(x);
    return (unsigned short)((u + 0x7FFFu + ((u >> 16) & 1u)) >> 16);
}
__device__ inline float b2f(unsigned short b) {
    return __uint_as_float((unsigned)b << 16);
}

// ======== setup: extract (ballot compaction) + weight transposes + feat->bf16 ====
// Wp [2][512][256] bf16: n = (hq*4+g)*16+hr <-> h=hq*16+hr, gate g (i,f,g,o)
// bp [2][512] fp32 same perm.  Wg1p/Wg2p [512][128] bf16: n = kg*128+hcol.
__global__ __launch_bounds__(256) void setup_kernel(
    const float* __restrict__ adj, const float* __restrict__ feat,
    const float* __restrict__ wih_f, const float* __restrict__ whh_f,
    const float* __restrict__ bih_f, const float* __restrict__ bhh_f,
    const float* __restrict__ wih_b, const float* __restrict__ whh_b,
    const float* __restrict__ bih_b, const float* __restrict__ bhh_b,
    const float* __restrict__ gw1, const float* __restrict__ gw2,
    float* __restrict__ dinv, int* __restrict__ ecnt,
    unsigned short* __restrict__ edges, unsigned* __restrict__ featb,
    unsigned short* __restrict__ Wp, float* __restrict__ bp,
    unsigned short* __restrict__ Wg1p, unsigned short* __restrict__ Wg2p)
{
    int b = blockIdx.x;
    __shared__ int cnt[KG];
    if (b < NN) {
        int i = b;
        int lane = threadIdx.x & 63;
        if (threadIdx.x < KG) cnt[threadIdx.x] = 0;
        __syncthreads();
        const float4* row = (const float4*)(adj + (size_t)i * NN * KG);
        unsigned long long below = (1ull << lane) - 1ull;
        for (int j = threadIdx.x; j < NN; j += 256) {
            float4 v = row[j];
#pragma unroll
            for (int k = 0; k < KG; ++k) {
                float comp = (k == 0) ? v.x : (k == 1) ? v.y : (k == 2) ? v.z : v.w;
                unsigned long long mask = __ballot(comp != 0.f);
                if (mask) {                       // wave-uniform
                    int base;
                    if (lane == 0) base = atomicAdd(&cnt[k], __popcll(mask));
                    base = __shfl(base, 0);
                    if (comp != 0.f) {
                        int p = base + (int)__popcll(mask & below);
                        if (p < CAP)
                            edges[((size_t)(k * NN + i)) * CAP + p] = (unsigned short)j;
                    }
                }
            }
        }
        __syncthreads();
        if (threadIdx.x < KG) {
            int c = cnt[threadIdx.x];
            ecnt[threadIdx.x * NN + i] = c > CAP ? CAP : c;
            dinv[threadIdx.x * NN + i] = rsqrtf((float)c + 1.0f);
        }
    } else if (b < NN + 1024) {                       // Wp: 262144 elems
        int t = (b - NN) * 256 + threadIdx.x;
        int dir = t >> 17, rem = t & 131071;
        int n = rem >> 8, k = rem & 255;
        int hq = n >> 6, g = (n >> 4) & 3, hr = n & 15;
        int row = g * HD + hq * 16 + hr;
        const float* wih = dir ? wih_b : wih_f;
        const float* whh = dir ? whh_b : whh_f;
        Wp[t] = f2b(k < HD ? wih[row * HD + k] : whh[row * HD + (k - HD)]);
    } else if (b < NN + 1280) {                       // Wg1p: 65536
        int t = (b - NN - 1024) * 256 + threadIdx.x;
        int n = t >> 7, k = t & 127;
        Wg1p[t] = f2b(gw1[(((size_t)(n >> 7)) * HD + k) * HD + (n & 127)]);
    } else if (b < NN + 1536) {                       // Wg2p: 65536
        int t = (b - NN - 1280) * 256 + threadIdx.x;
        int n = t >> 7, k = t & 127;
        Wg2p[t] = f2b(gw2[(((size_t)(n >> 7)) * HD + k) * HD + (n & 127)]);
    } else if (b < NN + 2560) {                       // featb: 262144 uint pairs
        int t = (b - NN - 1536) * 256 + threadIdx.x;
        float2 v = *(const float2*)&feat[2 * (size_t)t];
        featb[t] = (unsigned)f2b(v.x) | ((unsigned)f2b(v.y) << 16);
    } else {                                          // bp: 1024
        int t = (b - NN - 2560) * 256 + threadIdx.x;
        if (t < 1024) {
            int dir = t >> 9, n = t & 511;
            int hq = n >> 6, g = (n >> 4) & 3, hr = n & 15;
            int row = g * HD + hq * 16 + hr;
            bp[t] = dir ? (bih_b[row] + bhh_b[row]) : (bih_f[row] + bhh_f[row]);
        }
    }
}

// ======== GCN GEMM 1: Zs[kg] = dinv ⊙ (feat @ W1[kg]), bf16 out, tile 64x128 ====
__global__ __launch_bounds__(256) void gemm_gcn_mfma(
    const unsigned short* __restrict__ Ab,
    const unsigned short* __restrict__ Bp, const float* __restrict__ dinv,
    unsigned short* __restrict__ Cb)
{
    __shared__ unsigned short Abuf[64 * 40];
    __shared__ unsigned short Bbuf[128 * 40];
    int kg = blockIdx.x, m0 = blockIdx.y * 64;
    const unsigned short* A = Ab;
    int wid = threadIdx.x >> 6, lane = threadIdx.x & 63;
    int wm = wid >> 1, wn = wid & 1;
    int la = lane & 15, kb = (lane >> 4) * 8;
    f32x4 acc[2][4] = {};
    for (int ch = 0; ch < 4; ++ch) {
        {
            int t = threadIdx.x, r = t >> 2, q = t & 3;
            *(uint4*)&Abuf[r * 40 + q * 8] =
                *(const uint4*)&A[((size_t)(m0 + r)) * HD + ch * 32 + q * 8];
        }
#pragma unroll
        for (int it = 0; it < 2; ++it) {
            int f = threadIdx.x + it * 256;
            int r = f >> 2, q = f & 3;
            *(uint4*)&Bbuf[r * 40 + q * 8] =
                *(const uint4*)&Bp[((size_t)(kg * 128 + r)) * HD + ch * 32 + q * 8];
        }
        __syncthreads();
        bf16x8 a[2], bb[4];
#pragma unroll
        for (int m = 0; m < 2; ++m)
            a[m] = *(const bf16x8*)&Abuf[(wm * 32 + m * 16 + la) * 40 + kb];
#pragma unroll
        for (int n = 0; n < 4; ++n)
            bb[n] = *(const bf16x8*)&Bbuf[(wn * 64 + n * 16 + la) * 40 + kb];
#pragma unroll
        for (int m = 0; m < 2; ++m)
#pragma unroll
            for (int n = 0; n < 4; ++n)
                acc[m][n] = __builtin_amdgcn_mfma_f32_16x16x32_bf16(a[m], bb[n], acc[m][n], 0, 0, 0);
        __syncthreads();
    }
    unsigned short* Ck = Cb + (size_t)kg * NN * HD;
    const float* dv = dinv + kg * NN;
    int lj = lane >> 4;
#pragma unroll
    for (int m = 0; m < 2; ++m)
#pragma unroll
        for (int j = 0; j < 4; ++j) {
            int r = m0 + wm * 32 + m * 16 + lj * 4 + j;
            float d = dv[r];
#pragma unroll
            for (int n = 0; n < 4; ++n) {
                int col = wn * 64 + n * 16 + la;
                Ck[(size_t)r * HD + col] = f2b(acc[m][n][j] * d);
            }
        }
}

// ======== fused SpMM + GCN GEMM 2 ====
// Phase 1 (8 waves, 8 rows each): h1_i = di*(Σ_j Zs_j + Zs_i) + b1  -> bf16 LDS tile
// Phase 2: Zs2 = dinv ⊙ (h1 @ W2), 64x128 MFMA, K=128.
// Output MUST go to a different buffer than Zs (other blocks still gather from Zs).
__global__ __launch_bounds__(512) void spmm_gemm_fused(
    const unsigned* __restrict__ Zs, const float* __restrict__ dinv,
    const int* __restrict__ ecnt, const unsigned short* __restrict__ edges,
    const float* __restrict__ bias, const unsigned short* __restrict__ Bp,
    unsigned short* __restrict__ Cb)
{
    __shared__ unsigned short Alds[64 * 136];   // 17 KB, full-K h1 tile (2-way bank ok)
    __shared__ unsigned short Bbuf[128 * 40];   // 10 KB
    int kg = blockIdx.x, m0 = blockIdx.y * 64;
    int wid = threadIdx.x >> 6, lane = threadIdx.x & 63;
    const unsigned* Zk = Zs + (size_t)kg * NN * 64;
    // ---- phase 1: gather-reduce 8 rows per wave ----
    for (int rr = 0; rr < 8; ++rr) {
        int r = wid * 8 + rr;
        int i = m0 + r;
        int idx = (kg << 12) + i;
        int cnt = ecnt[idx];
        float di = dinv[idx];
        int myj = edges[(size_t)idx * CAP + lane];   // coalesced preload
        float ax = 0.f, ay = 0.f;
        for (int e = 0; e < cnt; e += 4) {           // wave-uniform control
            int rem = cnt - e;
            int j0 = __shfl(myj, e);
            int j1 = __shfl(myj, e + 1);
            int j2 = __shfl(myj, e + 2);
            int j3 = __shfl(myj, e + 3);
            unsigned z0 = Zk[(size_t)j0 * 64 + lane];
            unsigned z1 = (rem > 1) ? Zk[(size_t)j1 * 64 + lane] : 0u;
            unsigned z2 = (rem > 2) ? Zk[(size_t)j2 * 64 + lane] : 0u;
            unsigned z3 = (rem > 3) ? Zk[(size_t)j3 * 64 + lane] : 0u;
            ax += (b2f((unsigned short)z0) + b2f((unsigned short)z1))
                + (b2f((unsigned short)z2) + b2f((unsigned short)z3));
            ay += (b2f((unsigned short)(z0 >> 16)) + b2f((unsigned short)(z1 >> 16)))
                + (b2f((unsigned short)(z2 >> 16)) + b2f((unsigned short)(z3 >> 16)));
        }
        unsigned zi = Zk[(size_t)i * 64 + lane];     // self term (pre-scaled by di)
        ax += b2f((unsigned short)zi);
        ay += b2f((unsigned short)(zi >> 16));
        float2 bv = *(const float2*)(bias + kg * HD + 2 * lane);
        float ox = fmaf(di, ax, bv.x);
        float oy = fmaf(di, ay, bv.y);
        ((unsigned*)Alds)[r * 68 + lane] = (unsigned)f2b(ox) | ((unsigned)f2b(oy) << 16);
    }
    __syncthreads();
    // ---- phase 2: MFMA 64x128, K=128 ----
    int wm = wid >> 1, wn = wid & 1;                 // 8 waves: 4 M-blocks x 2 N-halves
    int la = lane & 15, kb = (lane >> 4) * 8;
    f32x4 acc[4] = {};
    for (int ch = 0; ch < 4; ++ch) {
        {
            int rb = threadIdx.x >> 2, q = threadIdx.x & 3;   // 512 = 128 rows x 4 quads
            *(uint4*)&Bbuf[rb * 40 + q * 8] =
                *(const uint4*)&Bp[((size_t)(kg * 128 + rb)) * HD + ch * 32 + q * 8];
        }
        __syncthreads();
        bf16x8 a = *(const bf16x8*)&Alds[(wm * 16 + la) * 136 + ch * 32 + kb];
#pragma unroll
        for (int n = 0; n < 4; ++n) {
            bf16x8 bb = *(const bf16x8*)&Bbuf[(wn * 64 + n * 16 + la) * 40 + kb];
            acc[n] = __builtin_amdgcn_mfma_f32_16x16x32_bf16(a, bb, acc[n], 0, 0, 0);
        }
        __syncthreads();
    }
    unsigned short* Ck = Cb + (size_t)kg * NN * HD;
    const float* dv = dinv + kg * NN;
    int lj = lane >> 4;
#pragma unroll
    for (int j = 0; j < 4; ++j) {
        int r = m0 + wm * 16 + lj * 4 + j;
        float d = dv[r];
#pragma unroll
        for (int n = 0; n < 4; ++n) {
            int col = wn * 64 + n * 16 + la;
            Ck[(size_t)r * HD + col] = f2b(acc[n][j] * d);
        }
    }
}

// ======== SpMM (standalone, layer 2): G2b = di*(Σ Zs2 + Zs2_i) + b2 ====
__global__ __launch_bounds__(256) void spmm_kernel(
    const unsigned* __restrict__ Zs, const float* __restrict__ dinv,
    const int* __restrict__ ecnt, const unsigned short* __restrict__ edges,
    const float* __restrict__ bias, unsigned* __restrict__ Outb)
{
    int wid = threadIdx.x >> 6, lane = threadIdx.x & 63;
    int idx = blockIdx.x * 4 + wid;   // idx = k*NN + i
    int k = idx >> 12, i = idx & (NN - 1);
    int cnt = ecnt[idx];
    float di = dinv[idx];
    const unsigned* Zk = Zs + (size_t)k * NN * 64;
    int myj = edges[(size_t)idx * CAP + lane];
    float ax = 0.f, ay = 0.f;
    for (int e = 0; e < cnt; e += 4) {
        int rem = cnt - e;
        int j0 = __shfl(myj, e);
        int j1 = __shfl(myj, e + 1);
        int j2 = __shfl(myj, e + 2);
        int j3 = __shfl(myj, e + 3);
        unsigned z0 = Zk[(size_t)j0 * 64 + lane];
        unsigned z1 = (rem > 1) ? Zk[(size_t)j1 * 64 + lane] : 0u;
        unsigned z2 = (rem > 2) ? Zk[(size_t)j2 * 64 + lane] : 0u;
        unsigned z3 = (rem > 3) ? Zk[(size_t)j3 * 64 + lane] : 0u;
        ax += (b2f((unsigned short)z0) + b2f((unsigned short)z1))
            + (b2f((unsigned short)z2) + b2f((unsigned short)z3));
        ay += (b2f((unsigned short)(z0 >> 16)) + b2f((unsigned short)(z1 >> 16)))
            + (b2f((unsigned short)(z2 >> 16)) + b2f((unsigned short)(z3 >> 16)));
    }
    unsigned zi = Zk[(size_t)i * 64 + lane];
    ax += b2f((unsigned short)zi);
    ay += b2f((unsigned short)(zi >> 16));
    float2 bv = *(const float2*)(bias + k * HD + 2 * lane);
    float ox = fmaf(di, ax, bv.x);
    float oy = fmaf(di, ay, bv.y);
    Outb[(size_t)idx * 64 + lane] = (unsigned)f2b(ox) | ((unsigned)f2b(oy) << 16);
}

// ======== fused biLSTM (unchanged) ====
__global__ __launch_bounds__(256) void lstm_fused(
    const unsigned short* __restrict__ G2b, unsigned short* __restrict__ hsb,
    const unsigned short* __restrict__ Wp, const float* __restrict__ bp)
{
    __shared__ unsigned short Bbuf[512 * 40];   // 40 KB
    __shared__ unsigned short Abuf[64 * 40];    // 5 KB
    __shared__ unsigned short hlds[64 * 136];   // 17 KB
    int m0 = blockIdx.x * 64;
    int dir = blockIdx.y;
    int wid = threadIdx.x >> 6, lane = threadIdx.x & 63;
    int la = lane & 15, lj = lane >> 4, kb = lj * 8;
    const unsigned short* B = Wp + (size_t)dir * 512 * 256;
    float c_st[4][2][4] = {};
    float bias[2][4];
#pragma unroll
    for (int ch = 0; ch < 2; ++ch)
#pragma unroll
        for (int g = 0; g < 4; ++g)
            bias[ch][g] = bp[dir * 512 + wid * 128 + (ch * 4 + g) * 16 + la];

    for (int t = 0; t < KG; ++t) {
        int kin = dir ? (KG - 1 - t) : t;
        f32x4 acc[4][8] = {};
        int nch = (t == 0) ? 4 : 8;
        for (int ch = 0; ch < nch; ++ch) {
            if (ch < 4) {
                int r = threadIdx.x >> 2, q = threadIdx.x & 3;
                *(uint4*)&Abuf[r * 40 + q * 8] =
                    *(const uint4*)&G2b[((size_t)kin * NN + m0 + r) * HD + ch * 32 + q * 8];
            }
#pragma unroll
            for (int it = 0; it < 8; ++it) {
                int f = threadIdx.x + it * 256;
                int r = f >> 2, q = f & 3;
                *(uint4*)&Bbuf[r * 40 + q * 8] =
                    *(const uint4*)&B[(size_t)r * 256 + ch * 32 + q * 8];
            }
            __syncthreads();
            bf16x8 bfr[8];
#pragma unroll
            for (int fi = 0; fi < 8; ++fi)
                bfr[fi] = *(const bf16x8*)&Bbuf[(wid * 128 + fi * 16 + la) * 40 + kb];
#pragma unroll
            for (int m = 0; m < 4; ++m) {
                bf16x8 afr = (ch < 4)
                    ? *(const bf16x8*)&Abuf[(m * 16 + la) * 40 + kb]
                    : *(const bf16x8*)&hlds[(m * 16 + la) * 136 + (ch - 4) * 32 + kb];
#pragma unroll
                for (int fi = 0; fi < 8; ++fi)
                    acc[m][fi] = __builtin_amdgcn_mfma_f32_16x16x32_bf16(afr, bfr[fi], acc[m][fi], 0, 0, 0);
            }
            __syncthreads();
        }
        unsigned short* hout = hsb + ((size_t)(dir * KG + kin) * NN) * HD;
#pragma unroll
        for (int m = 0; m < 4; ++m)
#pragma unroll
            for (int j = 0; j < 4; ++j) {
                int r = m * 16 + lj * 4 + j;
#pragma unroll
                for (int chf = 0; chf < 2; ++chf) {
                    int h = wid * 32 + chf * 16 + la;
                    float gi = acc[m][chf * 4 + 0][j] + bias[chf][0];
                    float gf = acc[m][chf * 4 + 1][j] + bias[chf][1];
                    float gg = acc[m][chf * 4 + 2][j] + bias[chf][2];
                    float go = acc[m][chf * 4 + 3][j] + bias[chf][3];
                    float cold = c_st[m][chf][j];
                    float si = 1.f / (1.f + __expf(-gi));
                    float sf = 1.f / (1.f + __expf(-gf));
                    float so = 1.f / (1.f + __expf(-go));
                    float e2g = __expf(2.f * gg);
                    float tg = 1.f - 2.f / (e2g + 1.f);
                    float cn = fmaf(sf, cold, si * tg);
                    float e2c = __expf(2.f * cn);
                    float tc = 1.f - 2.f / (e2c + 1.f);
                    c_st[m][chf][j] = cn;
                    unsigned short hb = f2b(so * tc);
                    hlds[r * 136 + h] = hb;
                    hout[(size_t)(m0 + r) * HD + h] = hb;
                }
            }
        __syncthreads();
    }
}

// ======== finalize: attn softmax over k -> pool (bf16 gnn) -> classify ========
__global__ __launch_bounds__(256) void finalize_kernel(
    const unsigned* __restrict__ gnnb, const unsigned* __restrict__ hsu,
    const float* __restrict__ rw, const float* __restrict__ ow,
    const float* __restrict__ ob, float* __restrict__ out)
{
    int wid = threadIdx.x >> 6, lane = threadIdx.x & 63;
    int n = blockIdx.x * 4 + wid;
    int u0 = 2 * lane;
    float w0 = rw[u0], w1 = rw[u0 + 1];
    float w2 = rw[HD + u0], w3 = rw[HD + u0 + 1];
    float lg[KG];
#pragma unroll
    for (int k = 0; k < KG; ++k) {
        unsigned hf = hsu[((size_t)k * NN + n) * 64 + lane];
        unsigned hb = hsu[((size_t)(KG + k) * NN + n) * 64 + lane];
        lg[k] = b2f((unsigned short)hf) * w0 + b2f((unsigned short)(hf >> 16)) * w1
              + b2f((unsigned short)hb) * w2 + b2f((unsigned short)(hb >> 16)) * w3;
    }
#pragma unroll
    for (int s = 32; s > 0; s >>= 1)
#pragma unroll
        for (int k = 0; k < KG; ++k) lg[k] += __shfl_xor(lg[k], s);
    float mx = lg[0];
#pragma unroll
    for (int k = 1; k < KG; ++k) mx = fmaxf(mx, lg[k]);
    float es[KG], se = 0.f;
#pragma unroll
    for (int k = 0; k < KG; ++k) { es[k] = __expf(lg[k] - mx); se += es[k]; }
    float inv = 1.f / se;
    float p0 = 0.f, p1 = 0.f;
#pragma unroll
    for (int k = 0; k < KG; ++k) {
        float a = es[k] * inv;
        unsigned g = gnnb[((size_t)k * NN + n) * 64 + lane];
        p0 = fmaf(a, b2f((unsigned short)g), p0);
        p1 = fmaf(a, b2f((unsigned short)(g >> 16)), p1);
    }
    float oc[NC];
#pragma unroll
    for (int c = 0; c < NC; ++c)
        oc[c] = p0 * ow[c * HD + u0] + p1 * ow[c * HD + u0 + 1];
#pragma unroll
    for (int s = 32; s > 0; s >>= 1)
#pragma unroll
        for (int c = 0; c < NC; ++c) oc[c] += __shfl_xor(oc[c], s);
    float omx = oc[0] + ob[0];
#pragma unroll
    for (int c = 0; c < NC; ++c) { oc[c] += ob[c]; omx = fmaxf(omx, oc[c]); }
    float osum = 0.f;
#pragma unroll
    for (int c = 0; c < NC; ++c) { oc[c] = __expf(oc[c] - omx); osum += oc[c]; }
    float oinv = 1.f / osum;
    if (lane < NC) out[(size_t)n * NC + lane] = oc[lane] * oinv;
}

extern "C" void kernel_launch(void* const* d_in, const int* in_sizes, int n_in,
                              void* d_out, int out_size, void* d_ws, size_t ws_size,
                              hipStream_t stream)
{
    const float* feat  = (const float*)d_in[0];
    const float* adj   = (const float*)d_in[1];
    const float* gw1   = (const float*)d_in[2];
    const float* gb1   = (const float*)d_in[3];
    const float* gw2   = (const float*)d_in[4];
    const float* gb2   = (const float*)d_in[5];
    const float* wih_f = (const float*)d_in[6];
    const float* whh_f = (const float*)d_in[7];
    const float* bih_f = (const float*)d_in[8];
    const float* bhh_f = (const float*)d_in[9];
    const float* wih_b = (const float*)d_in[10];
    const float* whh_b = (const float*)d_in[11];
    const float* bih_b = (const float*)d_in[12];
    const float* bhh_b = (const float*)d_in[13];
    const float* rw    = (const float*)d_in[14];
    const float* ow    = (const float*)d_in[16];
    const float* ob    = (const float*)d_in[17];
    float* out = (float*)d_out;

    char* ws = (char*)d_ws;
    float*          dinv  = (float*)(ws);                      // 64 KB
    int*            ecnt  = (int*)(ws + 65536);                // 64 KB
    unsigned short* edges = (unsigned short*)(ws + 131072);    // 2 MB   -> 2228224
    unsigned*       featb = (unsigned*)(ws + 2228224);         // 1 MB   -> 3276800
    unsigned short* Zs    = (unsigned short*)(ws + 3276800);   // 4 MB   -> 7471104
    unsigned short* Zs2   = (unsigned short*)(ws + 7471104);   // 4 MB   -> 11665408
    unsigned*       G2b   = (unsigned*)(ws + 11665408);        // 4 MB   -> 15859712
    unsigned short* hsb   = (unsigned short*)(ws + 15859712);  // 8 MB   -> 24248320
    unsigned short* Wp    = (unsigned short*)(ws + 24248320);  // 512 KB -> 24772608
    float*          bp    = (float*)(ws + 24772608);           // 4 KB   -> 24776704
    unsigned short* Wg1p  = (unsigned short*)(ws + 24776704);  // 128 KB -> 24907776
    unsigned short* Wg2p  = (unsigned short*)(ws + 24907776);  // 128 KB

    setup_kernel<<<NN + 2564, 256, 0, stream>>>(
        adj, feat, wih_f, whh_f, bih_f, bhh_f, wih_b, whh_b, bih_b, bhh_b,
        gw1, gw2, dinv, ecnt, edges, featb, Wp, bp, Wg1p, Wg2p);
    gemm_gcn_mfma<<<dim3(KG, 64), 256, 0, stream>>>(
        (const unsigned short*)featb, Wg1p, dinv, Zs);
    spmm_gemm_fused<<<dim3(KG, 64), 512, 0, stream>>>(
        (const unsigned*)Zs, dinv, ecnt, edges, gb1, Wg2p, Zs2);
    spmm_kernel<<<KG * NN / 4, 256, 0, stream>>>(
        (const unsigned*)Zs2, dinv, ecnt, edges, gb2, G2b);
    lstm_fused<<<dim3(64, 2), 256, 0, stream>>>(
        (const unsigned short*)G2b, hsb, Wp, bp);
    finalize_kernel<<<NN / 4, 256, 0, stream>>>(
        G2b, (const unsigned*)hsb, rw, ow, ob, out);
}

// Round 7
// 486.912 us; speedup vs baseline: 1.0490x; 1.0490x over previous
//
#include <hip/hip_runtime.h>
#include <hip/hip_bf16.h>

#define NN 4096
#define HD 128
#define KG 4
#define NC 10
#define CAP 64

typedef __attribute__((ext_vector_type(8))) short bf16x8;
typedef __attribute__((ext_vector_type(4))) float f32x4;

__device__ inline unsigned short f2b(float x) {   // fp32 -> bf16 RNE
    unsigned u = __float_as_uint(x);
    return (unsigned short)((u + 0x7FFFu + ((u >> 16) & 1u)) >> 16);
}
__device__ inline float b2f(unsigned short b) {
    return __uint_as_float((unsigned)b << 16);
}

// ======== setup: extract (ballot compaction) + weight transposes + feat->bf16 ====
// Wp [2][512][256] bf16: n = (hq*4+g)*16+hr <-> h=hq*16+hr, gate g (i,f,g,o)
// bp [2][512] fp32 same perm.  Wg1p/Wg2p [512][128] bf16: n = kg*128+hcol.
__global__ __launch_bounds__(256) void setup_kernel(
    const float* __restrict__ adj, const float* __restrict__ feat,
    const float* __restrict__ wih_f, const float* __restrict__ whh_f,
    const float* __restrict__ bih_f, const float* __restrict__ bhh_f,
    const float* __restrict__ wih_b, const float* __restrict__ whh_b,
    const float* __restrict__ bih_b, const float* __restrict__ bhh_b,
    const float* __restrict__ gw1, const float* __restrict__ gw2,
    float* __restrict__ dinv, int* __restrict__ ecnt,
    unsigned short* __restrict__ edges, unsigned* __restrict__ featb,
    unsigned short* __restrict__ Wp, float* __restrict__ bp,
    unsigned short* __restrict__ Wg1p, unsigned short* __restrict__ Wg2p)
{
    int b = blockIdx.x;
    __shared__ int cnt[KG];
    if (b < NN) {
        int i = b;
        int lane = threadIdx.x & 63;
        if (threadIdx.x < KG) cnt[threadIdx.x] = 0;
        __syncthreads();
        const float4* row = (const float4*)(adj + (size_t)i * NN * KG);
        unsigned long long below = (1ull << lane) - 1ull;
        for (int j = threadIdx.x; j < NN; j += 256) {
            float4 v = row[j];
#pragma unroll
            for (int k = 0; k < KG; ++k) {
                float comp = (k == 0) ? v.x : (k == 1) ? v.y : (k == 2) ? v.z : v.w;
                unsigned long long mask = __ballot(comp != 0.f);
                if (mask) {                       // wave-uniform
                    int base;
                    if (lane == 0) base = atomicAdd(&cnt[k], __popcll(mask));
                    base = __shfl(base, 0);
                    if (comp != 0.f) {
                        int p = base + (int)__popcll(mask & below);
                        if (p < CAP)
                            edges[((size_t)(k * NN + i)) * CAP + p] = (unsigned short)j;
                    }
                }
            }
        }
        __syncthreads();
        if (threadIdx.x < KG) {
            int c = cnt[threadIdx.x];
            ecnt[threadIdx.x * NN + i] = c > CAP ? CAP : c;
            dinv[threadIdx.x * NN + i] = rsqrtf((float)c + 1.0f);
        }
    } else if (b < NN + 1024) {                       // Wp: 262144 elems
        int t = (b - NN) * 256 + threadIdx.x;
        int dir = t >> 17, rem = t & 131071;
        int n = rem >> 8, k = rem & 255;
        int hq = n >> 6, g = (n >> 4) & 3, hr = n & 15;
        int row = g * HD + hq * 16 + hr;
        const float* wih = dir ? wih_b : wih_f;
        const float* whh = dir ? whh_b : whh_f;
        Wp[t] = f2b(k < HD ? wih[row * HD + k] : whh[row * HD + (k - HD)]);
    } else if (b < NN + 1280) {                       // Wg1p: 65536
        int t = (b - NN - 1024) * 256 + threadIdx.x;
        int n = t >> 7, k = t & 127;
        Wg1p[t] = f2b(gw1[(((size_t)(n >> 7)) * HD + k) * HD + (n & 127)]);
    } else if (b < NN + 1536) {                       // Wg2p: 65536
        int t = (b - NN - 1280) * 256 + threadIdx.x;
        int n = t >> 7, k = t & 127;
        Wg2p[t] = f2b(gw2[(((size_t)(n >> 7)) * HD + k) * HD + (n & 127)]);
    } else if (b < NN + 2560) {                       // featb: 262144 uint pairs
        int t = (b - NN - 1536) * 256 + threadIdx.x;
        float2 v = *(const float2*)&feat[2 * (size_t)t];
        featb[t] = (unsigned)f2b(v.x) | ((unsigned)f2b(v.y) << 16);
    } else {                                          // bp: 1024
        int t = (b - NN - 2560) * 256 + threadIdx.x;
        if (t < 1024) {
            int dir = t >> 9, n = t & 511;
            int hq = n >> 6, g = (n >> 4) & 3, hr = n & 15;
            int row = g * HD + hq * 16 + hr;
            bp[t] = dir ? (bih_b[row] + bhh_b[row]) : (bih_f[row] + bhh_f[row]);
        }
    }
}

// ======== GCN GEMM: Cb[kg] = dinv ⊙ (A @ W[kg]), bf16 in/out, tile 64x128 ====
__global__ __launch_bounds__(256) void gemm_gcn_mfma(
    const unsigned short* __restrict__ Ab, int a_per_k,
    const unsigned short* __restrict__ Bp, const float* __restrict__ dinv,
    unsigned short* __restrict__ Cb)
{
    __shared__ unsigned short Abuf[64 * 40];
    __shared__ unsigned short Bbuf[128 * 40];
    int kg = blockIdx.x, m0 = blockIdx.y * 64;
    const unsigned short* A = Ab + (a_per_k ? (size_t)kg * NN * HD : 0);
    int wid = threadIdx.x >> 6, lane = threadIdx.x & 63;
    int wm = wid >> 1, wn = wid & 1;
    int la = lane & 15, kb = (lane >> 4) * 8;
    f32x4 acc[2][4] = {};
    for (int ch = 0; ch < 4; ++ch) {
        {
            int t = threadIdx.x, r = t >> 2, q = t & 3;
            *(uint4*)&Abuf[r * 40 + q * 8] =
                *(const uint4*)&A[((size_t)(m0 + r)) * HD + ch * 32 + q * 8];
        }
#pragma unroll
        for (int it = 0; it < 2; ++it) {
            int f = threadIdx.x + it * 256;
            int r = f >> 2, q = f & 3;
            *(uint4*)&Bbuf[r * 40 + q * 8] =
                *(const uint4*)&Bp[((size_t)(kg * 128 + r)) * HD + ch * 32 + q * 8];
        }
        __syncthreads();
        bf16x8 a[2], bb[4];
#pragma unroll
        for (int m = 0; m < 2; ++m)
            a[m] = *(const bf16x8*)&Abuf[(wm * 32 + m * 16 + la) * 40 + kb];
#pragma unroll
        for (int n = 0; n < 4; ++n)
            bb[n] = *(const bf16x8*)&Bbuf[(wn * 64 + n * 16 + la) * 40 + kb];
#pragma unroll
        for (int m = 0; m < 2; ++m)
#pragma unroll
            for (int n = 0; n < 4; ++n)
                acc[m][n] = __builtin_amdgcn_mfma_f32_16x16x32_bf16(a[m], bb[n], acc[m][n], 0, 0, 0);
        __syncthreads();
    }
    unsigned short* Ck = Cb + (size_t)kg * NN * HD;
    const float* dv = dinv + kg * NN;
    int lj = lane >> 4;
#pragma unroll
    for (int m = 0; m < 2; ++m)
#pragma unroll
        for (int j = 0; j < 4; ++j) {
            int r = m0 + wm * 32 + m * 16 + lj * 4 + j;
            float d = dv[r];
#pragma unroll
            for (int n = 0; n < 4; ++n) {
                int col = wn * 64 + n * 16 + la;
                Ck[(size_t)r * HD + col] = f2b(acc[m][n][j] * d);
            }
        }
}

// ======== SpMM: Out_i = di*(Σ_j Zs_j + Zs_i) + b   (Zs pre-scaled bf16) ====
// Wave per row; edge list in registers, shfl-broadcast, 4 gathers in flight.
__global__ __launch_bounds__(256) void spmm_kernel(
    const unsigned* __restrict__ Zs, const float* __restrict__ dinv,
    const int* __restrict__ ecnt, const unsigned short* __restrict__ edges,
    const float* __restrict__ bias, unsigned* __restrict__ Outb)
{
    int wid = threadIdx.x >> 6, lane = threadIdx.x & 63;
    int idx = blockIdx.x * 4 + wid;   // idx = k*NN + i
    int k = idx >> 12, i = idx & (NN - 1);
    int cnt = ecnt[idx];
    float di = dinv[idx];
    const unsigned* Zk = Zs + (size_t)k * NN * 64;
    int myj = edges[(size_t)idx * CAP + lane];   // coalesced 128B preload
    float ax = 0.f, ay = 0.f;
    for (int e = 0; e < cnt; e += 4) {           // all control wave-uniform
        int rem = cnt - e;
        int j0 = __shfl(myj, e);
        int j1 = __shfl(myj, e + 1);
        int j2 = __shfl(myj, e + 2);
        int j3 = __shfl(myj, e + 3);
        unsigned z0 = Zk[(size_t)j0 * 64 + lane];
        unsigned z1 = (rem > 1) ? Zk[(size_t)j1 * 64 + lane] : 0u;
        unsigned z2 = (rem > 2) ? Zk[(size_t)j2 * 64 + lane] : 0u;
        unsigned z3 = (rem > 3) ? Zk[(size_t)j3 * 64 + lane] : 0u;
        ax += (b2f((unsigned short)z0) + b2f((unsigned short)z1))
            + (b2f((unsigned short)z2) + b2f((unsigned short)z3));
        ay += (b2f((unsigned short)(z0 >> 16)) + b2f((unsigned short)(z1 >> 16)))
            + (b2f((unsigned short)(z2 >> 16)) + b2f((unsigned short)(z3 >> 16)));
    }
    unsigned zi = Zk[(size_t)i * 64 + lane];     // self term (pre-scaled = di*z_i)
    ax += b2f((unsigned short)zi);
    ay += b2f((unsigned short)(zi >> 16));
    float2 bv = *(const float2*)(bias + k * HD + 2 * lane);
    float ox = fmaf(di, ax, bv.x);
    float oy = fmaf(di, ay, bv.y);
    Outb[(size_t)idx * 64 + lane] = (unsigned)f2b(ox) | ((unsigned)f2b(oy) << 16);
}

// ======== fused biLSTM: 32-row blocks for 2x occupancy ====
// Block = 32 rows x 1 dir, 4 waves; wave wid owns n-slice [wid*128, wid*128+128)
// = units [wid*32, wid*32+32) x gates. K=256: chunks 0-3 x-part (A=G2b),
// chunks 4-7 h-part (A from hlds). Recurrence is row-local -> block-local.
__global__ __launch_bounds__(256) void lstm_fused(
    const unsigned short* __restrict__ G2b, unsigned short* __restrict__ hsb,
    const unsigned short* __restrict__ Wp, const float* __restrict__ bp)
{
    __shared__ unsigned short Bbuf[512 * 40];   // 40 KB
    __shared__ unsigned short Abuf[32 * 40];    // 2.5 KB
    __shared__ unsigned short hlds[32 * 136];   // 8.5 KB
    int m0 = blockIdx.x * 32;
    int dir = blockIdx.y;
    int wid = threadIdx.x >> 6, lane = threadIdx.x & 63;
    int la = lane & 15, lj = lane >> 4, kb = lj * 8;
    const unsigned short* B = Wp + (size_t)dir * 512 * 256;
    float c_st[2][2][4] = {};
    float bias[2][4];
#pragma unroll
    for (int ch = 0; ch < 2; ++ch)
#pragma unroll
        for (int g = 0; g < 4; ++g)
            bias[ch][g] = bp[dir * 512 + wid * 128 + (ch * 4 + g) * 16 + la];

    for (int t = 0; t < KG; ++t) {
        int kin = dir ? (KG - 1 - t) : t;
        f32x4 acc[2][8] = {};
        int nch = (t == 0) ? 4 : 8;
        for (int ch = 0; ch < nch; ++ch) {
            if (ch < 4 && threadIdx.x < 128) {   // stage x chunk: 32 rows x 4 quads
                int r = threadIdx.x >> 2, q = threadIdx.x & 3;
                *(uint4*)&Abuf[r * 40 + q * 8] =
                    *(const uint4*)&G2b[((size_t)kin * NN + m0 + r) * HD + ch * 32 + q * 8];
            }
#pragma unroll
            for (int it = 0; it < 8; ++it) {     // stage B chunk [512][32]
                int f = threadIdx.x + it * 256;
                int r = f >> 2, q = f & 3;
                *(uint4*)&Bbuf[r * 40 + q * 8] =
                    *(const uint4*)&B[(size_t)r * 256 + ch * 32 + q * 8];
            }
            __syncthreads();
            bf16x8 bfr[8];
#pragma unroll
            for (int fi = 0; fi < 8; ++fi)
                bfr[fi] = *(const bf16x8*)&Bbuf[(wid * 128 + fi * 16 + la) * 40 + kb];
#pragma unroll
            for (int m = 0; m < 2; ++m) {
                bf16x8 afr = (ch < 4)
                    ? *(const bf16x8*)&Abuf[(m * 16 + la) * 40 + kb]
                    : *(const bf16x8*)&hlds[(m * 16 + la) * 136 + (ch - 4) * 32 + kb];
#pragma unroll
                for (int fi = 0; fi < 8; ++fi)
                    acc[m][fi] = __builtin_amdgcn_mfma_f32_16x16x32_bf16(afr, bfr[fi], acc[m][fi], 0, 0, 0);
            }
            __syncthreads();
        }
        unsigned short* hout = hsb + ((size_t)(dir * KG + kin) * NN) * HD;
#pragma unroll
        for (int m = 0; m < 2; ++m)
#pragma unroll
            for (int j = 0; j < 4; ++j) {
                int r = m * 16 + lj * 4 + j;
#pragma unroll
                for (int chf = 0; chf < 2; ++chf) {
                    int h = wid * 32 + chf * 16 + la;
                    float gi = acc[m][chf * 4 + 0][j] + bias[chf][0];
                    float gf = acc[m][chf * 4 + 1][j] + bias[chf][1];
                    float gg = acc[m][chf * 4 + 2][j] + bias[chf][2];
                    float go = acc[m][chf * 4 + 3][j] + bias[chf][3];
                    float cold = c_st[m][chf][j];
                    float si = 1.f / (1.f + __expf(-gi));
                    float sf = 1.f / (1.f + __expf(-gf));
                    float so = 1.f / (1.f + __expf(-go));
                    float e2g = __expf(2.f * gg);
                    float tg = 1.f - 2.f / (e2g + 1.f);
                    float cn = fmaf(sf, cold, si * tg);
                    float e2c = __expf(2.f * cn);
                    float tc = 1.f - 2.f / (e2c + 1.f);
                    c_st[m][chf][j] = cn;
                    unsigned short hb = f2b(so * tc);
                    hlds[r * 136 + h] = hb;
                    hout[(size_t)(m0 + r) * HD + h] = hb;
                }
            }
        __syncthreads();
    }
}

// ======== finalize: attn softmax over k -> pool (bf16 gnn) -> classify ========
__global__ __launch_bounds__(256) void finalize_kernel(
    const unsigned* __restrict__ gnnb, const unsigned* __restrict__ hsu,
    const float* __restrict__ rw, const float* __restrict__ ow,
    const float* __restrict__ ob, float* __restrict__ out)
{
    int wid = threadIdx.x >> 6, lane = threadIdx.x & 63;
    int n = blockIdx.x * 4 + wid;
    int u0 = 2 * lane;
    float w0 = rw[u0], w1 = rw[u0 + 1];
    float w2 = rw[HD + u0], w3 = rw[HD + u0 + 1];
    float lg[KG];
#pragma unroll
    for (int k = 0; k < KG; ++k) {
        unsigned hf = hsu[((size_t)k * NN + n) * 64 + lane];
        unsigned hb = hsu[((size_t)(KG + k) * NN + n) * 64 + lane];
        lg[k] = b2f((unsigned short)hf) * w0 + b2f((unsigned short)(hf >> 16)) * w1
              + b2f((unsigned short)hb) * w2 + b2f((unsigned short)(hb >> 16)) * w3;
    }
#pragma unroll
    for (int s = 32; s > 0; s >>= 1)
#pragma unroll
        for (int k = 0; k < KG; ++k) lg[k] += __shfl_xor(lg[k], s);
    float mx = lg[0];
#pragma unroll
    for (int k = 1; k < KG; ++k) mx = fmaxf(mx, lg[k]);
    float es[KG], se = 0.f;
#pragma unroll
    for (int k = 0; k < KG; ++k) { es[k] = __expf(lg[k] - mx); se += es[k]; }
    float inv = 1.f / se;
    float p0 = 0.f, p1 = 0.f;
#pragma unroll
    for (int k = 0; k < KG; ++k) {
        float a = es[k] * inv;
        unsigned g = gnnb[((size_t)k * NN + n) * 64 + lane];
        p0 = fmaf(a, b2f((unsigned short)g), p0);
        p1 = fmaf(a, b2f((unsigned short)(g >> 16)), p1);
    }
    float oc[NC];
#pragma unroll
    for (int c = 0; c < NC; ++c)
        oc[c] = p0 * ow[c * HD + u0] + p1 * ow[c * HD + u0 + 1];
#pragma unroll
    for (int s = 32; s > 0; s >>= 1)
#pragma unroll
        for (int c = 0; c < NC; ++c) oc[c] += __shfl_xor(oc[c], s);
    float omx = oc[0] + ob[0];
#pragma unroll
    for (int c = 0; c < NC; ++c) { oc[c] += ob[c]; omx = fmaxf(omx, oc[c]); }
    float osum = 0.f;
#pragma unroll
    for (int c = 0; c < NC; ++c) { oc[c] = __expf(oc[c] - omx); osum += oc[c]; }
    float oinv = 1.f / osum;
    if (lane < NC) out[(size_t)n * NC + lane] = oc[lane] * oinv;
}

extern "C" void kernel_launch(void* const* d_in, const int* in_sizes, int n_in,
                              void* d_out, int out_size, void* d_ws, size_t ws_size,
                              hipStream_t stream)
{
    const float* feat  = (const float*)d_in[0];
    const float* adj   = (const float*)d_in[1];
    const float* gw1   = (const float*)d_in[2];
    const float* gb1   = (const float*)d_in[3];
    const float* gw2   = (const float*)d_in[4];
    const float* gb2   = (const float*)d_in[5];
    const float* wih_f = (const float*)d_in[6];
    const float* whh_f = (const float*)d_in[7];
    const float* bih_f = (const float*)d_in[8];
    const float* bhh_f = (const float*)d_in[9];
    const float* wih_b = (const float*)d_in[10];
    const float* whh_b = (const float*)d_in[11];
    const float* bih_b = (const float*)d_in[12];
    const float* bhh_b = (const float*)d_in[13];
    const float* rw    = (const float*)d_in[14];
    const float* ow    = (const float*)d_in[16];
    const float* ob    = (const float*)d_in[17];
    float* out = (float*)d_out;

    char* ws = (char*)d_ws;
    float*          dinv  = (float*)(ws);                      // 64 KB
    int*            ecnt  = (int*)(ws + 65536);                // 64 KB
    unsigned short* edges = (unsigned short*)(ws + 131072);    // 2 MB   -> 2228224
    unsigned*       featb = (unsigned*)(ws + 2228224);         // 1 MB   -> 3276800
    unsigned short* Zs    = (unsigned short*)(ws + 3276800);   // 4 MB   -> 7471104
    unsigned*       G1b   = (unsigned*)(ws + 7471104);         // 4 MB   -> 11665408
    unsigned*       G2b   = (unsigned*)(ws + 11665408);        // 4 MB   -> 15859712
    unsigned short* hsb   = (unsigned short*)(ws + 15859712);  // 8 MB   -> 24248320
    unsigned short* Wp    = (unsigned short*)(ws + 24248320);  // 512 KB -> 24772608
    float*          bp    = (float*)(ws + 24772608);           // 4 KB   -> 24776704
    unsigned short* Wg1p  = (unsigned short*)(ws + 24776704);  // 128 KB -> 24907776
    unsigned short* Wg2p  = (unsigned short*)(ws + 24907776);  // 128 KB

    setup_kernel<<<NN + 2564, 256, 0, stream>>>(
        adj, feat, wih_f, whh_f, bih_f, bhh_f, wih_b, whh_b, bih_b, bhh_b,
        gw1, gw2, dinv, ecnt, edges, featb, Wp, bp, Wg1p, Wg2p);
    gemm_gcn_mfma<<<dim3(KG, 64), 256, 0, stream>>>(
        (const unsigned short*)featb, 0, Wg1p, dinv, Zs);
    spmm_kernel<<<KG * NN / 4, 256, 0, stream>>>(
        (const unsigned*)Zs, dinv, ecnt, edges, gb1, G1b);
    gemm_gcn_mfma<<<dim3(KG, 64), 256, 0, stream>>>(
        (const unsigned short*)G1b, 1, Wg2p, dinv, Zs);
    spmm_kernel<<<KG * NN / 4, 256, 0, stream>>>(
        (const unsigned*)Zs, dinv, ecnt, edges, gb2, G2b);
    lstm_fused<<<dim3(NN / 32, 2), 256, 0, stream>>>(
        (const unsigned short*)G2b, hsb, Wp, bp);
    finalize_kernel<<<NN / 4, 256, 0, stream>>>(
        G2b, (const unsigned*)hsb, rw, ow, ob, out);
}